// Round 16
// baseline (99.446 us; speedup 1.0000x reference)
//
#include <hip/hip_runtime.h>
#include <hip/hip_bf16.h>
#include <cstdint>

// GAT fused layer: B=4, N=2048, F=128, H=8, HD=16, all fp32 I/O.
// Identity: exp(leaky(si+sj)) = max(exp(si)exp(sj), exp(.2si)exp(.2sj))
// prep: blocks [0,4096) tpack (adj -> transposed u64 mask words, 1 chunk of
//   256 j per block), [4096,5120) proj (XW -> WxT bf16, EI={ei,ei5} float2,
//   EJ2={ej,ej5} float2 interleaved), block 5120 WoT.
// vshuf: wxT -> vfrag in MFMA-fragment order (r15-proven coalesced V).
// gat v16: 1024 blocks x 256 thr = (b, tile, head-half); 4 waves = 4 heads,
//   each wave full 2048-j loop -> row sums wave-local (no combine).
//   launch_bounds(256,8) -> 8 blocks/CU = 32 waves/CU with ~8KB LDS and the
//   r15 pipeline intact (V reg-prefetch, EJ2 LDS dbuf, SGPR masks +
//   inverse_ballot, barrier-paced). Branch-pair is the packed dim:
//   tt = {Ei,Ei5}*{Ej,Ej5}, p = max(tt.lo,tt.hi). Writes normalized h to ws.
// outproj: 512 blocks: h tile -> Wo + bias + ELU (r14-combine structure).

typedef float f32x2 __attribute__((ext_vector_type(2)));
typedef float f32x4 __attribute__((ext_vector_type(4)));
typedef __bf16 bf16x8 __attribute__((ext_vector_type(8)));
typedef unsigned long long u64;

__device__ __forceinline__ float lsel(float v, u64 m, u64 lanebit) {
#if __has_builtin(__builtin_amdgcn_inverse_ballot_w64)
    (void)lanebit;
    return __builtin_amdgcn_inverse_ballot_w64(m) ? v : 0.0f;
#else
    return (m & lanebit) ? v : 0.0f;
#endif
}

__global__ __launch_bounds__(256)
void prep_kernel(const float* __restrict__ x, const float* __restrict__ W,
                 const float* __restrict__ a, const float* __restrict__ Wo,
                 const int* __restrict__ adj,
                 unsigned short* __restrict__ wxT,
                 float2* __restrict__ EI, float2* __restrict__ EJ2,
                 float* __restrict__ WoT,
                 u64* __restrict__ tmask)
{
    const int t = threadIdx.x;

    if (blockIdx.x < 4096) {
        // ---- tpack: one 256-j chunk per block (halved serial chain vs r11)
        __shared__ int al[16][257];
        const int blk2 = blockIdx.x;
        const int b = blk2 >> 10;
        const int tile = (blk2 >> 3) & 127;
        const int jcc = blk2 & 7;            // 256-j chunk
        const int jc = jcc * 256;
        const int rowbase = b * 2048 + tile * 16;
        const int w = t >> 6, lane = t & 63;
        const int r = lane & 15, jg = lane >> 4;
        const int srow = t >> 4, scol = (t & 15) * 16;

        const int* gsrc = adj + (size_t)(rowbase + srow) * 2048 + jc + scol;
        #pragma unroll
        for (int q = 0; q < 4; ++q) {
            const int4 v = *reinterpret_cast<const int4*>(&gsrc[q * 4]);
            al[srow][scol + q * 4 + 0] = v.x;
            al[srow][scol + q * 4 + 1] = v.y;
            al[srow][scol + q * 4 + 2] = v.z;
            al[srow][scol + q * 4 + 3] = v.w;
        }
        __syncthreads();
        u64 myw = 0;
        #pragma unroll
        for (int kk = 0; kk < 2; ++kk) {
            const int c0 = w * 64 + kk * 32 + jg * 8;
            const int4 a0 = *reinterpret_cast<const int4*>(&al[r][c0]);
            const int4 a1 = *reinterpret_cast<const int4*>(&al[r][c0 + 4]);
            const int av[8] = {a0.x, a0.y, a0.z, a0.w, a1.x, a1.y, a1.z, a1.w};
            #pragma unroll
            for (int e = 0; e < 8; ++e) {
                const u64 bal = __ballot(av[e] != 0);
                const int widx = kk * 8 + e;
                if (lane == widx) myw = bal;
            }
        }
        const int jtw = jcc * 4 + w;
        if (lane < 16)
            tmask[((size_t)(b * 128 + tile) * 32 + jtw) * 16 + lane] = myw;
        return;
    }

    // ---- proj: blocks [4096,5120), WoT block 5120 (t<128 active)
    const int blk = blockIdx.x - 4096;
    if (blk == 1024) {
        if (t < 128)
            for (int k = 0; k < 128; ++k)
                WoT[k * 128 + t] = Wo[t * 128 + k];
        return;
    }
    __shared__ float xl[8 * 128];
    __shared__ float xw[8 * 128];
    const int row0 = blk * 8;
    if (t < 128) {
        #pragma unroll
        for (int r = 0; r < 8; ++r)
            xl[r * 128 + t] = x[(size_t)(row0 + r) * 128 + t];
    }
    __syncthreads();

    if (t < 128) {
        float acc[8] = {0.f, 0.f, 0.f, 0.f, 0.f, 0.f, 0.f, 0.f};
        for (int k = 0; k < 128; k += 4) {
            const float w0 = W[(k + 0) * 128 + t];
            const float w1 = W[(k + 1) * 128 + t];
            const float w2 = W[(k + 2) * 128 + t];
            const float w3 = W[(k + 3) * 128 + t];
            #pragma unroll
            for (int r = 0; r < 8; ++r) {
                const float4 xv = *reinterpret_cast<const float4*>(&xl[r * 128 + k]);
                acc[r] += xv.x * w0 + xv.y * w1 + xv.z * w2 + xv.w * w3;
            }
        }
        #pragma unroll
        for (int r = 0; r < 8; ++r) xw[r * 128 + t] = acc[r];
    }
    __syncthreads();

    if (t < 128) {
        const int b = row0 >> 11, n0 = row0 & 2047;
        bf16x8 st;
        #pragma unroll
        for (int r = 0; r < 8; ++r) st[r] = (__bf16)xw[r * 128 + t];
        *reinterpret_cast<bf16x8*>(&wxT[((size_t)(b * 128 + t)) * 2048 + n0]) = st;

        const int r = t >> 4, h = (t >> 1) & 7, s = t & 1;
        float dot = 0.f;
        #pragma unroll
        for (int d = 0; d < 16; ++d)
            dot += xw[r * 128 + h * 16 + d] * a[h * 32 + s * 16 + d];
        float2 ev; ev.x = __expf(dot); ev.y = __expf(0.2f * dot);
        const int idx = (b * 8 + h) * 2048 + n0 + r;
        if (s) EJ2[idx] = ev; else EI[idx] = ev;
    }
}

// wxT [b*128+f][2048 n] -> vfrag [((b*8+h)*64 + w32)*64 + lane] (r15-proven)
__global__ __launch_bounds__(256)
void vshuf_kernel(const unsigned short* __restrict__ wxT,
                  unsigned short* __restrict__ vfrag)
{
    const int gid = blockIdx.x * 256 + threadIdx.x;   // 0..131071
    const int lane = gid & 63;
    const int w32 = (gid >> 6) & 63;
    const int bh = gid >> 12;                          // b*8 + h
    const int b = bh >> 3, h = bh & 7;
    const int f = h * 16 + (lane & 15);
    const int j = w32 * 32 + (lane >> 4) * 8;
    const bf16x8 v = *reinterpret_cast<const bf16x8*>(
        &wxT[((size_t)(b * 128 + f)) * 2048 + j]);
    *reinterpret_cast<bf16x8*>(&vfrag[(size_t)gid * 8]) = v;
}

__global__ __launch_bounds__(256, 8)
void gat_kernel(const u64* __restrict__ tmask,
                const unsigned short* __restrict__ vfrag,
                const float2* __restrict__ EI, const float2* __restrict__ EJ2,
                float* __restrict__ hnorm)
{
    const int tid = threadIdx.x;
    const int hw = tid >> 6;             // local head 0..3
    const int lane = tid & 63;
    const int r = lane & 15;             // A-frag row / B-frag col (feature)
    const int jg = lane >> 4;
    const int jaof = jg * 8;
    const u64 lanebit = 1ull << lane;
    // XCD-aware bijective swizzle over 1024 blocks; (b,tile) in high bits so
    // both head-halves of a tile land on the same XCD.
    const int bid = (blockIdx.x & 7) * 128 + (blockIdx.x >> 3);
    const int tg = bid >> 1;             // 0..511 = b*128 + tile
    const int hg = bid & 1;              // head half
    const int b = tg >> 7;
    const int tile = tg & 127;
    const int ibase = tile << 4;
    const int h = hg * 4 + hw;

    __shared__ __align__(16) float2 EjL[2][4][128];   // 8 KB

    const int eb = (b * 8 + h) * 2048;
    const float2 q0 = EI[eb + ibase + r];
    f32x2 Eipk; Eipk[0] = q0.x; Eipk[1] = q0.y;       // {exp(ei), exp(.2ei)}
    const u64* tmrow = tmask + (size_t)(b * 128 + tile) * 512;
    const unsigned short* vfr = vfrag + (size_t)(b * 8 + h) * 64 * 64 * 8;
    const float2* EJ2G = EJ2 + eb;

    f32x4 acc  = {0.f, 0.f, 0.f, 0.f};
    f32x4 accS = {0.f, 0.f, 0.f, 0.f};
    bf16x8 ones;
    #pragma unroll
    for (int e2 = 0; e2 < 8; ++e2) ones[e2] = (__bf16)1.0f;

    bf16x8 vC0, vC1, vC2, vC3, vN0, vN1, vN2, vN3;
    // ---- prologue: V chunk 0 (w32 0..3) -> regs, EJ2 chunk 0 -> LDS buf 0
    vC0 = *reinterpret_cast<const bf16x8*>(&vfr[(0 * 64 + lane) * 8]);
    vC1 = *reinterpret_cast<const bf16x8*>(&vfr[(1 * 64 + lane) * 8]);
    vC2 = *reinterpret_cast<const bf16x8*>(&vfr[(2 * 64 + lane) * 8]);
    vC3 = *reinterpret_cast<const bf16x8*>(&vfr[(3 * 64 + lane) * 8]);
    {
        const float4 s0 = *reinterpret_cast<const float4*>(&EJ2G[lane * 2]);
        *reinterpret_cast<float4*>(&EjL[0][hw][lane * 2]) = s0;
    }
    __syncthreads();

    int cur = 0;
    for (int c = 0; c < 16; ++c) {
        // ---- issue next chunk's loads (c=15: V wraps in-bounds; EJ2
        //      over-read lands in the next ws buffer, staged, never computed)
        const int w32n = ((c + 1) & 15) * 4;
        const int jn = (c + 1) * 128;
        vN0 = *reinterpret_cast<const bf16x8*>(&vfr[((w32n + 0) * 64 + lane) * 8]);
        vN1 = *reinterpret_cast<const bf16x8*>(&vfr[((w32n + 1) * 64 + lane) * 8]);
        vN2 = *reinterpret_cast<const bf16x8*>(&vfr[((w32n + 2) * 64 + lane) * 8]);
        vN3 = *reinterpret_cast<const bf16x8*>(&vfr[((w32n + 3) * 64 + lane) * 8]);
        const float4 snq = *reinterpret_cast<const float4*>(&EJ2G[jn + lane * 2]);
        __builtin_amdgcn_sched_barrier(0);

        // ---- masks for current chunk (block-uniform -> scalar loads)
        const u64* tmw = tmrow + c * 32;
        u64 mwA[16], mwB[16];
        #pragma unroll
        for (int e2 = 0; e2 < 16; ++e2) mwA[e2] = tmw[e2];
        #pragma unroll
        for (int e2 = 0; e2 < 16; ++e2) mwB[e2] = tmw[16 + e2];

        // ---- compute current chunk: 4 kk x (EJ2 from LDS, V from regs)
        #pragma unroll
        for (int kk = 0; kk < 4; ++kk) {
            const float2* ejp = &EjL[cur][hw][kk * 32 + jaof];  // 8 float2
            const bf16x8 v = (kk == 0) ? vC0 : (kk == 1) ? vC1 : (kk == 2) ? vC2 : vC3;
            const u64* mwp = (kk < 2) ? mwA : mwB;
            const int mof = (kk & 1) * 8;
            bf16x8 afr;
            #pragma unroll
            for (int e2 = 0; e2 < 8; ++e2) {
                const float2 q = ejp[e2];
                f32x2 tq; tq[0] = q.x; tq[1] = q.y;
                const f32x2 tt = Eipk * tq;            // {Ei*Ej, Ei5*Ej5}
                const float p = fmaxf(tt[0], tt[1]);   // exp(leaky(d))
                afr[e2] = (__bf16)lsel(p, mwp[mof + e2], lanebit);
            }
            acc  = __builtin_amdgcn_mfma_f32_16x16x32_bf16(afr, v,    acc,  0, 0, 0);
            accS = __builtin_amdgcn_mfma_f32_16x16x32_bf16(afr, ones, accS, 0, 0, 0);
        }

        // ---- stage next EJ2 into other buffer; barrier drains vmcnt
        const int nb = cur ^ 1;
        *reinterpret_cast<float4*>(&EjL[nb][hw][lane * 2]) =
            *reinterpret_cast<const float4*>(&snq);
        __syncthreads();
        vC0 = vN0; vC1 = vN1; vC2 = vN2; vC3 = vN3;
        cur = nb;
    }

    // ---- normalize + write h (C/D: col = r feature, row = jg*4+q)
    #pragma unroll
    for (int q = 0; q < 4; ++q) {
        const int row = jg * 4 + q;
        const float inv = (accS[q] > 0.f) ? 1.f / accS[q] : 0.f;  // empty row -> 0
        hnorm[(size_t)(b * 2048 + ibase + row) * 128 + h * 16 + r] = acc[q] * inv;
    }
}

__global__ __launch_bounds__(256)
void outproj_kernel(const float* __restrict__ hnorm, const float* __restrict__ WoT,
                    const float* __restrict__ bo, float* __restrict__ out)
{
    const int tid = threadIdx.x;
    const int bid = (blockIdx.x & 7) * 64 + (blockIdx.x >> 3);
    const int b = bid >> 7;
    const int tile = bid & 127;
    const int ibase = tile << 4;

    __shared__ float hl[16][128];
    const float* src = hnorm + (size_t)(b * 2048 + ibase) * 128;
    #pragma unroll
    for (int k = 0; k < 8; ++k) {
        const int idx = k * 256 + tid;        // 0..2047
        hl[idx >> 7][idx & 127] = src[idx];
    }
    __syncthreads();

    const int f = tid & 127;
    const int rg = tid >> 7;
    float o[8] = {0.f, 0.f, 0.f, 0.f, 0.f, 0.f, 0.f, 0.f};
    for (int k = 0; k < 128; k += 4) {
        const float w0 = WoT[(k + 0) * 128 + f];
        const float w1 = WoT[(k + 1) * 128 + f];
        const float w2 = WoT[(k + 2) * 128 + f];
        const float w3 = WoT[(k + 3) * 128 + f];
        #pragma unroll
        for (int q = 0; q < 8; ++q) {
            const float4 hv = *reinterpret_cast<const float4*>(&hl[rg * 8 + q][k]);
            o[q] += hv.x * w0 + hv.y * w1 + hv.z * w2 + hv.w * w3;
        }
    }
    const float bv = bo[f];
    #pragma unroll
    for (int q = 0; q < 8; ++q) {
        float v = o[q] + bv;
        v = (v > 0.f) ? v : (__expf(v) - 1.f);
        out[(size_t)(b * 2048 + ibase + rg * 8 + q) * 128 + f] = v;
    }
}

extern "C" void kernel_launch(void* const* d_in, const int* in_sizes, int n_in,
                              void* d_out, int out_size, void* d_ws, size_t ws_size,
                              hipStream_t stream) {
    const float* x   = (const float*)d_in[0];
    const int*   adj = (const int*)d_in[1];
    const float* W   = (const float*)d_in[2];
    const float* a   = (const float*)d_in[3];
    const float* Wo  = (const float*)d_in[4];
    const float* bo  = (const float*)d_in[5];
    float* out = (float*)d_out;

    // ws: wxT 2MB | EI 512K | EJ2 512K | WoT 64K | tmask 2MB | vfrag 2MB | hnorm 4MB
    char* ws = (char*)d_ws;
    unsigned short* wxT = (unsigned short*)ws;
    float2* EI  = (float2*)(ws + (size_t)2 * 1024 * 1024);
    float2* EJ2 = EI + 4 * 8 * 2048;
    float* WoT  = (float*)(EJ2 + 4 * 8 * 2048);
    u64* tmask = (u64*)(WoT + 128 * 128);
    unsigned short* vfrag = (unsigned short*)(tmask + (size_t)512 * 512);
    float* hnorm = (float*)(vfrag + (size_t)1024 * 1024);

    prep_kernel<<<dim3(4096 + 1025), dim3(256), 0, stream>>>(
        x, W, a, Wo, adj, wxT, EI, EJ2, WoT, tmask);
    vshuf_kernel<<<dim3(512), dim3(256), 0, stream>>>(wxT, vfrag);
    gat_kernel<<<dim3(1024), dim3(256), 0, stream>>>(
        tmask, vfrag, EI, EJ2, hnorm);
    outproj_kernel<<<dim3(512), dim3(256), 0, stream>>>(hnorm, WoT, bo, out);
}

// Round 17
// 70.643 us; speedup vs baseline: 1.4077x; 1.4077x over previous
//
#include <hip/hip_runtime.h>
#include <hip/hip_bf16.h>
#include <cstdint>

// GAT fused layer: B=4, N=2048, F=128, H=8, HD=16, all fp32 I/O.
// Identity: exp(leaky(si+sj)) = max(exp(si)exp(sj), exp(.2si)exp(.2sj))
// prep: blocks [0,2048) tpack (r11-proven 2-chunk transposed mask pack),
//   [2048,3072) proj -> vfrag DIRECT (MFMA-fragment order; wxT+vshuf
//   deleted) + EI/EJ2 interleaved exp tables, block 3072 WoT.
// gat_part: 2048 blocks x 256 thr = (b, tile, head-half, j-half); 4 waves =
//   4 heads, each 1024 j. launch_bounds(256,6) keeps VGPR ~<=85 so the r15
//   pipeline survives (r16 lesson: (256,8) crushed VGPR to 32). V coalesced
//   reg-prefetch one chunk ahead, EJ2 LDS dbuf (bank-conflict-free, r16),
//   SGPR masks + inverse_ballot, barrier-paced. Writes fp32 partials.
// combine: r14-proven: pair-add jh halves, normalize, out-proj + ELU.

typedef float f32x2 __attribute__((ext_vector_type(2)));
typedef float f32x4 __attribute__((ext_vector_type(4)));
typedef __bf16 bf16x8 __attribute__((ext_vector_type(8)));
typedef unsigned long long u64;

__device__ __forceinline__ float lsel(float v, u64 m, u64 lanebit) {
#if __has_builtin(__builtin_amdgcn_inverse_ballot_w64)
    (void)lanebit;
    return __builtin_amdgcn_inverse_ballot_w64(m) ? v : 0.0f;
#else
    return (m & lanebit) ? v : 0.0f;
#endif
}

__global__ __launch_bounds__(256)
void prep_kernel(const float* __restrict__ x, const float* __restrict__ W,
                 const float* __restrict__ a, const float* __restrict__ Wo,
                 const int* __restrict__ adj,
                 unsigned short* __restrict__ vfrag,
                 float2* __restrict__ EI, float2* __restrict__ EJ2,
                 float* __restrict__ WoT,
                 u64* __restrict__ tmask)
{
    const int t = threadIdx.x;

    if (blockIdx.x < 2048) {
        // ---- tpack: adj -> transposed mask words (r11-proven)
        __shared__ int al[16][257];
        const int blk2 = blockIdx.x;
        const int b = blk2 >> 9;
        const int tile = (blk2 >> 2) & 127;
        const int jq = blk2 & 3;
        const int rowbase = b * 2048 + tile * 16;
        const int w = t >> 6, lane = t & 63;
        const int r = lane & 15, jg = lane >> 4;
        const int srow = t >> 4, scol = (t & 15) * 16;

        #pragma unroll
        for (int cc = 0; cc < 2; ++cc) {
            const int jc = jq * 512 + cc * 256;
            const int* gsrc = adj + (size_t)(rowbase + srow) * 2048 + jc + scol;
            #pragma unroll
            for (int q = 0; q < 4; ++q) {
                const int4 v = *reinterpret_cast<const int4*>(&gsrc[q * 4]);
                al[srow][scol + q * 4 + 0] = v.x;
                al[srow][scol + q * 4 + 1] = v.y;
                al[srow][scol + q * 4 + 2] = v.z;
                al[srow][scol + q * 4 + 3] = v.w;
            }
            __syncthreads();
            u64 myw = 0;
            #pragma unroll
            for (int kk = 0; kk < 2; ++kk) {
                const int c0 = w * 64 + kk * 32 + jg * 8;
                const int4 a0 = *reinterpret_cast<const int4*>(&al[r][c0]);
                const int4 a1 = *reinterpret_cast<const int4*>(&al[r][c0 + 4]);
                const int av[8] = {a0.x, a0.y, a0.z, a0.w, a1.x, a1.y, a1.z, a1.w};
                #pragma unroll
                for (int e = 0; e < 8; ++e) {
                    const u64 bal = __ballot(av[e] != 0);
                    const int widx = kk * 8 + e;
                    if (lane == widx) myw = bal;
                }
            }
            __syncthreads();
            const int jtw = jq * 8 + cc * 4 + w;
            if (lane < 16)
                tmask[((size_t)(b * 128 + tile) * 32 + jtw) * 16 + lane] = myw;
        }
        return;
    }

    // ---- proj: blocks [2048,3072), WoT block 3072 (t<128 active)
    const int blk = blockIdx.x - 2048;
    if (blk == 1024) {
        if (t < 128)
            for (int k = 0; k < 128; ++k)
                WoT[k * 128 + t] = Wo[t * 128 + k];
        return;
    }
    __shared__ float xl[8 * 128];
    __shared__ float xw[8 * 128];
    const int row0 = blk * 8;
    if (t < 128) {
        #pragma unroll
        for (int r = 0; r < 8; ++r)
            xl[r * 128 + t] = x[(size_t)(row0 + r) * 128 + t];
    }
    __syncthreads();

    if (t < 128) {
        float acc[8] = {0.f, 0.f, 0.f, 0.f, 0.f, 0.f, 0.f, 0.f};
        for (int k = 0; k < 128; k += 4) {
            const float w0 = W[(k + 0) * 128 + t];
            const float w1 = W[(k + 1) * 128 + t];
            const float w2 = W[(k + 2) * 128 + t];
            const float w3 = W[(k + 3) * 128 + t];
            #pragma unroll
            for (int r = 0; r < 8; ++r) {
                const float4 xv = *reinterpret_cast<const float4*>(&xl[r * 128 + k]);
                acc[r] += xv.x * w0 + xv.y * w1 + xv.z * w2 + xv.w * w3;
            }
        }
        #pragma unroll
        for (int r = 0; r < 8; ++r) xw[r * 128 + t] = acc[r];
    }
    __syncthreads();

    if (t < 128) {
        const int b = row0 >> 11, n0 = row0 & 2047;
        // vfrag DIRECT: thread t=f owns 8 consecutive n = one (w32, jg) slot.
        bf16x8 st;
        #pragma unroll
        for (int r = 0; r < 8; ++r) st[r] = (__bf16)xw[r * 128 + t];
        const int hh = t >> 4, rr = t & 15;
        const int w32 = n0 >> 5, jgp = (n0 >> 3) & 3;
        *reinterpret_cast<bf16x8*>(
            &vfrag[(((size_t)(b * 8 + hh) * 64 + w32) * 64 + jgp * 16 + rr) * 8]) = st;

        const int r = t >> 4, h = (t >> 1) & 7, s = t & 1;
        float dot = 0.f;
        #pragma unroll
        for (int d = 0; d < 16; ++d)
            dot += xw[r * 128 + h * 16 + d] * a[h * 32 + s * 16 + d];
        float2 ev; ev.x = __expf(dot); ev.y = __expf(0.2f * dot);
        const int idx = (b * 8 + h) * 2048 + n0 + r;
        if (s) EJ2[idx] = ev; else EI[idx] = ev;
    }
}

__global__ __launch_bounds__(256, 6)
void gat_part(const u64* __restrict__ tmask,
              const unsigned short* __restrict__ vfrag,
              const float2* __restrict__ EI, const float2* __restrict__ EJ2,
              float* __restrict__ pacc, float* __restrict__ psum)
{
    const int tid = threadIdx.x;
    const int hw = tid >> 6;             // local head 0..3
    const int lane = tid & 63;
    const int r = lane & 15;             // A-frag row / B-frag col (feature)
    const int jg = lane >> 4;
    const u64 lanebit = 1ull << lane;
    // all 4 subs of one (b,tile) share an XCD (r14-proven mapping)
    const int x = blockIdx.x & 7, w = blockIdx.x >> 3;
    const int tg = x * 64 + (w & 63);    // 0..511 = b*128+tile
    const int sub = w >> 6;              // 0..3
    const int jh = sub >> 1, hg = sub & 1;
    const int b = tg >> 7;
    const int tile = tg & 127;
    const int ibase = tile << 4;
    const int h = hg * 4 + hw;

    __shared__ __align__(16) float2 EjL[2][4][128];   // 8 KB

    const int eb = (b * 8 + h) * 2048;
    const float2 q0 = EI[eb + ibase + r];
    f32x2 Eipk; Eipk[0] = q0.x; Eipk[1] = q0.y;       // {exp(ei), exp(.2ei)}
    const u64* tmrow = tmask + (size_t)(b * 128 + tile) * 512;
    const unsigned short* vfr = vfrag + (size_t)(b * 8 + h) * 64 * 64 * 8;
    const float2* EJ2G = EJ2 + eb;

    f32x4 acc  = {0.f, 0.f, 0.f, 0.f};
    f32x4 accS = {0.f, 0.f, 0.f, 0.f};
    bf16x8 ones;
    #pragma unroll
    for (int e2 = 0; e2 < 8; ++e2) ones[e2] = (__bf16)1.0f;

    const int jbase = jh * 1024;
    const int wbase = jh * 32;

    bf16x8 vC0, vC1, vC2, vC3, vN0, vN1, vN2, vN3;
    // ---- prologue: V chunk 0 -> regs, EJ2 chunk 0 -> LDS buf 0
    vC0 = *reinterpret_cast<const bf16x8*>(&vfr[((wbase + 0) * 64 + lane) * 8]);
    vC1 = *reinterpret_cast<const bf16x8*>(&vfr[((wbase + 1) * 64 + lane) * 8]);
    vC2 = *reinterpret_cast<const bf16x8*>(&vfr[((wbase + 2) * 64 + lane) * 8]);
    vC3 = *reinterpret_cast<const bf16x8*>(&vfr[((wbase + 3) * 64 + lane) * 8]);
    {
        const float4 s0 = *reinterpret_cast<const float4*>(&EJ2G[jbase + lane * 2]);
        *reinterpret_cast<float4*>(&EjL[0][hw][lane * 2]) = s0;
    }
    __syncthreads();

    int cur = 0;
    for (int c = 0; c < 8; ++c) {
        // ---- issue next chunk's loads (c=7 wraps within half: in-bounds,
        //      staged/rotated but never computed)
        const int cn = (c + 1) & 7;
        const int w32n = wbase + cn * 4;
        const int jn = jbase + cn * 128;
        vN0 = *reinterpret_cast<const bf16x8*>(&vfr[((w32n + 0) * 64 + lane) * 8]);
        vN1 = *reinterpret_cast<const bf16x8*>(&vfr[((w32n + 1) * 64 + lane) * 8]);
        vN2 = *reinterpret_cast<const bf16x8*>(&vfr[((w32n + 2) * 64 + lane) * 8]);
        vN3 = *reinterpret_cast<const bf16x8*>(&vfr[((w32n + 3) * 64 + lane) * 8]);
        const float4 snq = *reinterpret_cast<const float4*>(&EJ2G[jn + lane * 2]);
        __builtin_amdgcn_sched_barrier(0);

        // ---- masks for current chunk (block-uniform -> scalar loads)
        const u64* tmw = tmrow + (jh * 16 + c * 2) * 16;
        u64 mwA[16], mwB[16];
        #pragma unroll
        for (int e2 = 0; e2 < 16; ++e2) mwA[e2] = tmw[e2];
        #pragma unroll
        for (int e2 = 0; e2 < 16; ++e2) mwB[e2] = tmw[16 + e2];

        // ---- compute current chunk: 4 kk x (EJ2 from LDS, V from regs)
        #pragma unroll
        for (int kk = 0; kk < 4; ++kk) {
            const float2* ejp = &EjL[cur][hw][kk * 32 + jg * 8];
            const bf16x8 v = (kk == 0) ? vC0 : (kk == 1) ? vC1 : (kk == 2) ? vC2 : vC3;
            const u64* mwp = (kk < 2) ? mwA : mwB;
            const int mof = (kk & 1) * 8;
            bf16x8 afr;
            #pragma unroll
            for (int e2 = 0; e2 < 8; ++e2) {
                const float2 q = ejp[e2];
                f32x2 tq; tq[0] = q.x; tq[1] = q.y;
                const f32x2 tt = Eipk * tq;            // {Ei*Ej, Ei5*Ej5}
                const float p = fmaxf(tt[0], tt[1]);   // exp(leaky(d))
                afr[e2] = (__bf16)lsel(p, mwp[mof + e2], lanebit);
            }
            acc  = __builtin_amdgcn_mfma_f32_16x16x32_bf16(afr, v,    acc,  0, 0, 0);
            accS = __builtin_amdgcn_mfma_f32_16x16x32_bf16(afr, ones, accS, 0, 0, 0);
        }

        // ---- stage next EJ2; barrier drains vmcnt (V loads complete)
        const int nb = cur ^ 1;
        *reinterpret_cast<float4*>(&EjL[nb][hw][lane * 2]) =
            *reinterpret_cast<const float4*>(&snq);
        __syncthreads();
        vC0 = vN0; vC1 = vN1; vC2 = vN2; vC3 = vN3;
        cur = nb;
    }

    // ---- partials (r14 layout). C/D: col = r (feature), row = jg*4+q.
    const size_t pb = (size_t)((b * 128 + tile) * 2 + jh);
    float* pa = pacc + pb * 2048;
    float* ps = psum + pb * 128;
    #pragma unroll
    for (int q = 0; q < 4; ++q) {
        const int row = jg * 4 + q;
        pa[row * 128 + hg * 64 + hw * 16 + r] = acc[q];
        if (r == 0) ps[(hg * 4 + hw) * 16 + row] = accS[q];
    }
}

__global__ __launch_bounds__(256)
void combine_kernel(const float* __restrict__ pacc, const float* __restrict__ psum,
                    const float* __restrict__ WoT, const float* __restrict__ bo,
                    float* __restrict__ out)
{
    const int tid = threadIdx.x;
    const int bid = (blockIdx.x & 7) * 64 + (blockIdx.x >> 3);
    const int b = bid >> 7;
    const int tile = bid & 127;
    const int ibase = tile << 4;

    __shared__ float hl[16][128];
    const size_t pb0 = (size_t)((b * 128 + tile) * 2);
    const float* pa0 = pacc + pb0 * 2048;
    const float* pa1 = pa0 + 2048;
    const float* ps0 = psum + pb0 * 128;
    const float* ps1 = ps0 + 128;

    #pragma unroll
    for (int k = 0; k < 8; ++k) {
        const int idx = k * 256 + tid;        // 0..2047
        const int row = idx >> 7, f = idx & 127, h = f >> 4;
        const float num = pa0[idx] + pa1[idx];
        const float den = ps0[h * 16 + row] + ps1[h * 16 + row];
        const float inv = (den > 0.f) ? 1.f / den : 0.f;   // empty row -> 0
        hl[row][f] = num * inv;
    }
    __syncthreads();

    const int f = tid & 127;
    const int rg = tid >> 7;
    float o[8] = {0.f, 0.f, 0.f, 0.f, 0.f, 0.f, 0.f, 0.f};
    for (int k = 0; k < 128; k += 4) {
        const float w0 = WoT[(k + 0) * 128 + f];
        const float w1 = WoT[(k + 1) * 128 + f];
        const float w2 = WoT[(k + 2) * 128 + f];
        const float w3 = WoT[(k + 3) * 128 + f];
        #pragma unroll
        for (int q = 0; q < 8; ++q) {
            const float4 hv = *reinterpret_cast<const float4*>(&hl[rg * 8 + q][k]);
            o[q] += hv.x * w0 + hv.y * w1 + hv.z * w2 + hv.w * w3;
        }
    }
    const float bv = bo[f];
    #pragma unroll
    for (int q = 0; q < 8; ++q) {
        float v = o[q] + bv;
        v = (v > 0.f) ? v : (__expf(v) - 1.f);
        out[(size_t)(b * 2048 + ibase + rg * 8 + q) * 128 + f] = v;
    }
}

extern "C" void kernel_launch(void* const* d_in, const int* in_sizes, int n_in,
                              void* d_out, int out_size, void* d_ws, size_t ws_size,
                              hipStream_t stream) {
    const float* x   = (const float*)d_in[0];
    const int*   adj = (const int*)d_in[1];
    const float* W   = (const float*)d_in[2];
    const float* a   = (const float*)d_in[3];
    const float* Wo  = (const float*)d_in[4];
    const float* bo  = (const float*)d_in[5];
    float* out = (float*)d_out;

    // ws: vfrag 2MB | EI 512K | EJ2 512K | WoT 64K | tmask 2MB | pacc 8MB |
    //     psum 512K   (~13.6 MB)
    char* ws = (char*)d_ws;
    unsigned short* vfrag = (unsigned short*)ws;
    float2* EI  = (float2*)(ws + (size_t)2 * 1024 * 1024);
    float2* EJ2 = EI + 4 * 8 * 2048;
    float* WoT  = (float*)(EJ2 + 4 * 8 * 2048);
    u64* tmask = (u64*)(WoT + 128 * 128);
    float* pacc = (float*)(tmask + (size_t)512 * 512);
    float* psum = pacc + (size_t)1024 * 2048;

    prep_kernel<<<dim3(2048 + 1025), dim3(256), 0, stream>>>(
        x, W, a, Wo, adj, vfrag, EI, EJ2, WoT, tmask);
    gat_part<<<dim3(2048), dim3(256), 0, stream>>>(
        tmask, vfrag, EI, EJ2, pacc, psum);
    combine_kernel<<<dim3(512), dim3(256), 0, stream>>>(
        pacc, psum, WoT, bo, out);
}